// Round 1
// baseline (2160.996 us; speedup 1.0000x reference)
//
#include <hip/hip_runtime.h>
#include <hip/hip_bf16.h>
#include <math.h>

#define N_NODES 50000
#define N_EDGES 1600000
#define NFEAT 512
#define NHID 256
#define NCLASS 40

// ---------------------------------------------------------------- CSR build

__global__ void zero_i32(int* __restrict__ p, int n) {
    int i = blockIdx.x * blockDim.x + threadIdx.x;
    if (i < n) p[i] = 0;
}

__global__ void hist_kernel(const int* __restrict__ dst, int* __restrict__ cnt, int n) {
    int i = blockIdx.x * blockDim.x + threadIdx.x;
    int stride = gridDim.x * blockDim.x;
    for (; i < n; i += stride) atomicAdd(&cnt[dst[i]], 1);
}

__global__ __launch_bounds__(1024) void exscan_kernel(const int* __restrict__ cnt,
                                                      int* __restrict__ rowptr,
                                                      int* __restrict__ cursor, int n) {
    __shared__ int buf[1024];
    __shared__ int carry_s;
    int tid = threadIdx.x;
    if (tid == 0) carry_s = 0;
    __syncthreads();
    for (int base = 0; base < n; base += 1024) {
        int i = base + tid;
        int v = (i < n) ? cnt[i] : 0;
        buf[tid] = v;
        __syncthreads();
        #pragma unroll
        for (int off = 1; off < 1024; off <<= 1) {
            int t = (tid >= off) ? buf[tid - off] : 0;
            __syncthreads();
            buf[tid] += t;
            __syncthreads();
        }
        int incl = buf[tid];
        int carry = carry_s;
        if (i < n) {
            int ex = carry + incl - v;
            rowptr[i] = ex;
            cursor[i] = ex;
        }
        __syncthreads();
        if (tid == 1023) carry_s = carry + incl;
        __syncthreads();
    }
    if (tid == 0) rowptr[n] = carry_s;
}

__global__ void scatter_kernel(const int* __restrict__ src, const int* __restrict__ dst,
                               const float* __restrict__ vals, int* __restrict__ cursor,
                               int* __restrict__ csrc, float* __restrict__ cval, int n) {
    int i = blockIdx.x * blockDim.x + threadIdx.x;
    int stride = gridDim.x * blockDim.x;
    for (; i < n; i += stride) {
        int d = dst[i];
        int p = atomicAdd(&cursor[d], 1);
        csrc[p] = src[i];
        cval[p] = vals[i];
    }
}

// ---------------------------------------------------------------- dense GEMM (f32)
// C[M,N] = A[M,K] @ B[K,N] (+bias) (+= if accumulate)

#define TM 64
#define TN 64
#define TK 16

__global__ __launch_bounds__(256) void gemm_f32(const float* __restrict__ A, int M, int K,
                                                const float* __restrict__ B, int N,
                                                const float* __restrict__ bias,
                                                float* __restrict__ C, int accumulate) {
    __shared__ float As[TK][TM];
    __shared__ float Bs[TK][TN];

    int row0 = blockIdx.y * TM;
    int col0 = blockIdx.x * TN;
    int tid = threadIdx.x;
    int tx = tid & 15;       // N dim
    int ty = tid >> 4;       // M dim

    float acc[4][4] = {};

    for (int k0 = 0; k0 < K; k0 += TK) {
        // A tile: 64 rows x 16 cols; thread -> row tid/4, cols (tid%4)*4
        {
            int r = tid >> 2;
            int c = (tid & 3) * 4;
            int gr = row0 + r;
            float4 a = make_float4(0.f, 0.f, 0.f, 0.f);
            if (gr < M) a = *reinterpret_cast<const float4*>(A + (size_t)gr * K + k0 + c);
            As[c + 0][r] = a.x;
            As[c + 1][r] = a.y;
            As[c + 2][r] = a.z;
            As[c + 3][r] = a.w;
        }
        // B tile: 16 rows x 64 cols; thread -> row tid/16, cols (tid%16)*4
        {
            int r = tid >> 4;
            int c4 = (tid & 15) * 4;
            int gc = col0 + c4;
            const float* Brow = B + (size_t)(k0 + r) * N;
            float4 b;
            if (gc + 3 < N) {
                b = *reinterpret_cast<const float4*>(Brow + gc);
            } else {
                b.x = (gc + 0 < N) ? Brow[gc + 0] : 0.f;
                b.y = (gc + 1 < N) ? Brow[gc + 1] : 0.f;
                b.z = (gc + 2 < N) ? Brow[gc + 2] : 0.f;
                b.w = (gc + 3 < N) ? Brow[gc + 3] : 0.f;
            }
            Bs[r][c4 + 0] = b.x;
            Bs[r][c4 + 1] = b.y;
            Bs[r][c4 + 2] = b.z;
            Bs[r][c4 + 3] = b.w;
        }
        __syncthreads();
        #pragma unroll
        for (int k = 0; k < TK; ++k) {
            float4 av = *reinterpret_cast<const float4*>(&As[k][ty * 4]);
            float4 bv = *reinterpret_cast<const float4*>(&Bs[k][tx * 4]);
            float a4[4] = {av.x, av.y, av.z, av.w};
            float b4[4] = {bv.x, bv.y, bv.z, bv.w};
            #pragma unroll
            for (int i = 0; i < 4; ++i)
                #pragma unroll
                for (int j = 0; j < 4; ++j)
                    acc[i][j] = fmaf(a4[i], b4[j], acc[i][j]);
        }
        __syncthreads();
    }

    #pragma unroll
    for (int i = 0; i < 4; ++i) {
        int gr = row0 + ty * 4 + i;
        if (gr >= M) continue;
        #pragma unroll
        for (int j = 0; j < 4; ++j) {
            int gc = col0 + tx * 4 + j;
            if (gc >= N) continue;
            float v = acc[i][j];
            if (bias) v += bias[gc];
            size_t idx = (size_t)gr * N + gc;
            if (accumulate) v += C[idx];
            C[idx] = v;
        }
    }
}

// ---------------------------------------------------------------- SpMM D=256, fused bias+relu+residual
// out[r] = relu(sum_e val*Y[src] + bias) + res[r]   (out may alias res)

__global__ __launch_bounds__(256) void spmm_epi256(const int* __restrict__ rowptr,
                                                   const int* __restrict__ csrc,
                                                   const float* __restrict__ cval,
                                                   const float* __restrict__ Y,
                                                   const float* __restrict__ bias,
                                                   const float* __restrict__ res,
                                                   float* __restrict__ out) {
    int row = (blockIdx.x * blockDim.x + threadIdx.x) >> 6;
    if (row >= N_NODES) return;
    int lane = threadIdx.x & 63;
    int col = lane * 4;
    int beg = rowptr[row];
    int end = rowptr[row + 1];
    float4 acc = make_float4(0.f, 0.f, 0.f, 0.f);
    for (int e = beg; e < end; ++e) {
        float v = cval[e];
        int s = csrc[e];
        float4 h = *reinterpret_cast<const float4*>(Y + (size_t)s * NHID + col);
        acc.x = fmaf(v, h.x, acc.x);
        acc.y = fmaf(v, h.y, acc.y);
        acc.z = fmaf(v, h.z, acc.z);
        acc.w = fmaf(v, h.w, acc.w);
    }
    float4 bb = *reinterpret_cast<const float4*>(bias + col);
    float4 rr = *reinterpret_cast<const float4*>(res + (size_t)row * NHID + col);
    float4 o;
    o.x = fmaxf(acc.x + bb.x, 0.f) + rr.x;
    o.y = fmaxf(acc.y + bb.y, 0.f) + rr.y;
    o.z = fmaxf(acc.z + bb.z, 0.f) + rr.z;
    o.w = fmaxf(acc.w + bb.w, 0.f) + rr.w;
    *reinterpret_cast<float4*>(out + (size_t)row * NHID + col) = o;
}

// ---------------------------------------------------------------- SpMM D=40 + bias + log_softmax

__global__ __launch_bounds__(256) void spmm40_lsm(const int* __restrict__ rowptr,
                                                  const int* __restrict__ csrc,
                                                  const float* __restrict__ cval,
                                                  const float* __restrict__ Y,
                                                  const float* __restrict__ bias,
                                                  float* __restrict__ out) {
    int row = (blockIdx.x * blockDim.x + threadIdx.x) >> 6;
    if (row >= N_NODES) return;
    int lane = threadIdx.x & 63;
    bool act = lane < NCLASS;
    int beg = rowptr[row];
    int end = rowptr[row + 1];
    float acc = 0.f;
    for (int e = beg; e < end; ++e) {
        float v = cval[e];
        int s = csrc[e];
        float h = act ? Y[(size_t)s * NCLASS + lane] : 0.f;
        acc = fmaf(v, h, acc);
    }
    float x = act ? (acc + bias[lane]) : -INFINITY;
    float m = x;
    #pragma unroll
    for (int off = 32; off > 0; off >>= 1) m = fmaxf(m, __shfl_xor(m, off));
    float ex = act ? __expf(x - m) : 0.f;
    float ssum = ex;
    #pragma unroll
    for (int off = 32; off > 0; off >>= 1) ssum += __shfl_xor(ssum, off);
    float ls = logf(ssum);
    if (act) out[(size_t)row * NCLASS + lane] = x - m - ls;
}

// ---------------------------------------------------------------- launch

extern "C" void kernel_launch(void* const* d_in, const int* in_sizes, int n_in,
                              void* d_out, int out_size, void* d_ws, size_t ws_size,
                              hipStream_t stream) {
    const float* x     = (const float*)d_in[0];
    const int*   esrc  = (const int*)d_in[1];
    const int*   edst  = (const int*)d_in[2];
    const float* evals = (const float*)d_in[3];
    const float* W0 = (const float*)d_in[4];
    const float* b0 = (const float*)d_in[5];
    const float* W1 = (const float*)d_in[6];
    const float* b1 = (const float*)d_in[7];
    const float* W2 = (const float*)d_in[8];
    const float* b2 = (const float*)d_in[9];
    const float* W3 = (const float*)d_in[10];
    const float* b3 = (const float*)d_in[11];
    const float* W5 = (const float*)d_in[12];
    const float* b5 = (const float*)d_in[13];
    float* out = (float*)d_out;

    char* ws = (char*)d_ws;
    size_t off = 0;
    auto alloc = [&](size_t bytes) {
        char* p = ws + off;
        off = (off + bytes + 255) & ~(size_t)255;
        return p;
    };
    float* bufX1 = (float*)alloc(sizeof(float) * (size_t)N_NODES * NHID);
    float* bufX2 = (float*)alloc(sizeof(float) * (size_t)N_NODES * NHID);
    float* bufX3 = (float*)alloc(sizeof(float) * (size_t)N_NODES * NHID);
    float* bufX4 = (float*)alloc(sizeof(float) * (size_t)N_NODES * NHID);
    float* bufY  = (float*)alloc(sizeof(float) * (size_t)N_NODES * NHID);
    float* bufY5 = (float*)alloc(sizeof(float) * (size_t)N_NODES * NCLASS);
    int* cnt    = (int*)alloc(sizeof(int) * N_NODES);
    int* rowptr = (int*)alloc(sizeof(int) * (N_NODES + 1));
    int* cursor = (int*)alloc(sizeof(int) * N_NODES);
    int* csrc   = (int*)alloc(sizeof(int) * N_EDGES);
    float* cval = (float*)alloc(sizeof(float) * N_EDGES);
    (void)ws_size;

    // ---- CSR build (by dst)
    zero_i32<<<(N_NODES + 255) / 256, 256, 0, stream>>>(cnt, N_NODES);
    hist_kernel<<<2048, 256, 0, stream>>>(edst, cnt, N_EDGES);
    exscan_kernel<<<1, 1024, 0, stream>>>(cnt, rowptr, cursor, N_NODES);
    scatter_kernel<<<2048, 256, 0, stream>>>(esrc, edst, evals, cursor, csrc, cval, N_EDGES);

    dim3 blk(256);
    int mtiles = (N_NODES + TM - 1) / TM;

    // z = x@W0 + b0  -> bufX1 (residual for layer 1)
    gemm_f32<<<dim3(NHID / TN, mtiles), blk, 0, stream>>>(x, N_NODES, NFEAT, W0, NHID, b0, bufX1, 0);
    // y1 = x@W1 -> bufY ; x1 = relu(spmm(y1)+b1) + z  (in place on bufX1)
    gemm_f32<<<dim3(NHID / TN, mtiles), blk, 0, stream>>>(x, N_NODES, NFEAT, W1, NHID, nullptr, bufY, 0);
    spmm_epi256<<<(N_NODES * 64) / 256, blk, 0, stream>>>(rowptr, csrc, cval, bufY, b1, bufX1, bufX1);

    // layer 2: y = x1@W2 ; x2 = relu(spmm+b2) + x1
    gemm_f32<<<dim3(NHID / TN, mtiles), blk, 0, stream>>>(bufX1, N_NODES, NHID, W2, NHID, nullptr, bufY, 0);
    spmm_epi256<<<(N_NODES * 64) / 256, blk, 0, stream>>>(rowptr, csrc, cval, bufY, b2, bufX1, bufX2);

    // layer 3: y = x2@W2 ; x3 = relu(spmm+b2) + x2
    gemm_f32<<<dim3(NHID / TN, mtiles), blk, 0, stream>>>(bufX2, N_NODES, NHID, W2, NHID, nullptr, bufY, 0);
    spmm_epi256<<<(N_NODES * 64) / 256, blk, 0, stream>>>(rowptr, csrc, cval, bufY, b2, bufX2, bufX3);

    // layer 4: y = x3@W3 ; x4 = relu(spmm+b3) + x3
    gemm_f32<<<dim3(NHID / TN, mtiles), blk, 0, stream>>>(bufX3, N_NODES, NHID, W3, NHID, nullptr, bufY, 0);
    spmm_epi256<<<(N_NODES * 64) / 256, blk, 0, stream>>>(rowptr, csrc, cval, bufY, b3, bufX3, bufX4);

    // y5 = concat(x4,x3,x2,x1) @ W5  (4 accumulating parts, W5 is [1024,40])
    gemm_f32<<<dim3(1, mtiles), blk, 0, stream>>>(bufX4, N_NODES, NHID, W5 + 0 * NHID * NCLASS, NCLASS, nullptr, bufY5, 0);
    gemm_f32<<<dim3(1, mtiles), blk, 0, stream>>>(bufX3, N_NODES, NHID, W5 + 1 * NHID * NCLASS, NCLASS, nullptr, bufY5, 1);
    gemm_f32<<<dim3(1, mtiles), blk, 0, stream>>>(bufX2, N_NODES, NHID, W5 + 2 * NHID * NCLASS, NCLASS, nullptr, bufY5, 1);
    gemm_f32<<<dim3(1, mtiles), blk, 0, stream>>>(bufX1, N_NODES, NHID, W5 + 3 * NHID * NCLASS, NCLASS, nullptr, bufY5, 1);

    // x5 = spmm(y5) + b5 ; out = log_softmax(x5)
    spmm40_lsm<<<(N_NODES * 64) / 256, blk, 0, stream>>>(rowptr, csrc, cval, bufY5, b5, out);
}

// Round 2
// 1271.134 us; speedup vs baseline: 1.7001x; 1.7001x over previous
//
#include <hip/hip_runtime.h>
#include <math.h>
#include <stdint.h>

#define N_NODES 50000
#define N_EDGES 1600000
#define NFEAT 512
#define NHID 256
#define NCLASS 40
#define MPAD 50048  // 391 * 128

typedef _Float16 half8 __attribute__((ext_vector_type(8)));
typedef _Float16 half4v __attribute__((ext_vector_type(4)));
typedef float floatx4 __attribute__((ext_vector_type(4)));

__device__ __forceinline__ void gload_lds16(const void* g, void* l) {
    __builtin_amdgcn_global_load_lds((const __attribute__((address_space(1))) void*)g,
                                     (__attribute__((address_space(3))) void*)l, 16, 0, 0);
}

// ---------------------------------------------------------------- CSR build

__global__ void zero_i32(int* __restrict__ p, int n) {
    int i = blockIdx.x * blockDim.x + threadIdx.x;
    if (i < n) p[i] = 0;
}

__global__ void hist_kernel(const int* __restrict__ dst, int* __restrict__ cnt, int n) {
    int i = blockIdx.x * blockDim.x + threadIdx.x;
    int stride = gridDim.x * blockDim.x;
    for (; i < n; i += stride) atomicAdd(&cnt[dst[i]], 1);
}

__global__ __launch_bounds__(1024) void exscan_kernel(const int* __restrict__ cnt,
                                                      int* __restrict__ rowptr,
                                                      int* __restrict__ cursor, int n) {
    __shared__ int buf[1024];
    __shared__ int carry_s;
    int tid = threadIdx.x;
    if (tid == 0) carry_s = 0;
    __syncthreads();
    for (int base = 0; base < n; base += 1024) {
        int i = base + tid;
        int v = (i < n) ? cnt[i] : 0;
        buf[tid] = v;
        __syncthreads();
        #pragma unroll
        for (int off = 1; off < 1024; off <<= 1) {
            int t = (tid >= off) ? buf[tid - off] : 0;
            __syncthreads();
            buf[tid] += t;
            __syncthreads();
        }
        int incl = buf[tid];
        int carry = carry_s;
        if (i < n) {
            int ex = carry + incl - v;
            rowptr[i] = ex;
            cursor[i] = ex;
        }
        __syncthreads();
        if (tid == 1023) carry_s = carry + incl;
        __syncthreads();
    }
    if (tid == 0) rowptr[n] = carry_s;
}

__global__ void scatter_kernel(const int* __restrict__ src, const int* __restrict__ dst,
                               const float* __restrict__ vals, int* __restrict__ cursor,
                               int2* __restrict__ cev, int n) {
    int i = blockIdx.x * blockDim.x + threadIdx.x;
    int stride = gridDim.x * blockDim.x;
    for (; i < n; i += stride) {
        int d = dst[i];
        int p = atomicAdd(&cursor[d], 1);
        cev[p] = make_int2(src[i], __float_as_int(vals[i]));
    }
}

// ---------------------------------------------------------------- conversions

__global__ void conv_x_kernel(const float* __restrict__ x, _Float16* __restrict__ xh, int total8) {
    int id = blockIdx.x * blockDim.x + threadIdx.x;
    if (id >= total8) return;
    const float4* p = (const float4*)x + (size_t)id * 2;
    float4 a = p[0], b = p[1];
    half8 h;
    h[0] = (_Float16)a.x; h[1] = (_Float16)a.y; h[2] = (_Float16)a.z; h[3] = (_Float16)a.w;
    h[4] = (_Float16)b.x; h[5] = (_Float16)b.y; h[6] = (_Float16)b.z; h[7] = (_Float16)b.w;
    *((half8*)xh + id) = h;
}

// W [K][N] f32 -> BT [Npad][K] f16 (transposed, zero-padded rows)
__global__ void conv_w_kernel(const float* __restrict__ W, _Float16* __restrict__ BT,
                              int K, int N, int Npad) {
    int id = blockIdx.x * blockDim.x + threadIdx.x;
    if (id >= Npad * K) return;
    int n = id / K;
    int k = id - n * K;
    BT[id] = (n < N) ? (_Float16)W[(size_t)k * N + n] : (_Float16)0.f;
}

// ---------------------------------------------------------------- f16 MFMA GEMM
// C[M,N] = A[M,K] * BT[N,K]^T ; A may be split into up to 4 row-major parts of
// kPerPart columns each (K-concat).  Output: f16 and/or f32, optional bias.

template<int BN>
__global__ __launch_bounds__(256, 2)
void gemm_f16(const _Float16* __restrict__ A0, const _Float16* __restrict__ A1,
              const _Float16* __restrict__ A2, const _Float16* __restrict__ A3,
              int kPerPart, int K,
              const _Float16* __restrict__ BT,
              const float* __restrict__ bias,
              _Float16* __restrict__ outH, float* __restrict__ outF,
              int M, int N) {
    constexpr int WN = BN / 2;
    constexpr int FN = WN / 16;
    __shared__ _Float16 As[128 * 64];
    __shared__ _Float16 Bs[BN * 64];

    const int tid = threadIdx.x;
    const int w = tid >> 6;
    const int lane = tid & 63;
    const int row0 = blockIdx.y * 128;
    const int col0 = blockIdx.x * BN;

    const int wr = w >> 1;
    const int wc = w & 1;
    const int mi = lane & 15;
    const int ksel = lane >> 4;

    // staging constants: lane -> (row-in-8, swizzled source col in elems)
    const int srow = lane >> 3;
    const int scol = ((lane & 7) ^ srow) << 3;

    floatx4 acc[4][FN];
    #pragma unroll
    for (int i = 0; i < 4; ++i)
        #pragma unroll
        for (int j = 0; j < FN; ++j)
            acc[i][j] = (floatx4)0.f;

    for (int k0 = 0; k0 < K; k0 += 64) {
        int part = k0 / kPerPart;
        int kloc = k0 - part * kPerPart;
        const _Float16* Ap = (part == 0) ? A0 : (part == 1) ? A1 : (part == 2) ? A2 : A3;

        // stage A tile: 128 rows x 64 f16 (row = 128B), 16 wave-issues of 1KB
        #pragma unroll
        for (int j = 0; j < 4; ++j) {
            int rowblk = (j * 4 + w) * 8;
            const _Float16* src = Ap + (size_t)(row0 + rowblk + srow) * kPerPart + kloc + scol;
            gload_lds16(src, (char*)As + rowblk * 128);
        }
        // stage B tile: BN rows x 64 f16
        #pragma unroll
        for (int j = 0; j < BN / 32; ++j) {
            int nblk = (j * 4 + w) * 8;
            const _Float16* src = BT + (size_t)(col0 + nblk + srow) * K + k0 + scol;
            gload_lds16(src, (char*)Bs + nblk * 128);
        }
        asm volatile("s_waitcnt vmcnt(0)" ::: "memory");
        __syncthreads();

        half8 a[2][4];
        half8 b[2][FN];
        #pragma unroll
        for (int kk = 0; kk < 2; ++kk) {
            int kb = kk * 64 + (ksel << 4);
            #pragma unroll
            for (int fm = 0; fm < 4; ++fm) {
                int r = wr * 64 + fm * 16 + mi;
                int byte = kb ^ ((r & 7) << 4);
                a[kk][fm] = *(const half8*)((const char*)As + r * 128 + byte);
            }
            #pragma unroll
            for (int fn = 0; fn < FN; ++fn) {
                int n = wc * WN + fn * 16 + mi;
                int byte = kb ^ ((n & 7) << 4);
                b[kk][fn] = *(const half8*)((const char*)Bs + n * 128 + byte);
            }
        }
        #pragma unroll
        for (int kk = 0; kk < 2; ++kk)
            #pragma unroll
            for (int fm = 0; fm < 4; ++fm)
                #pragma unroll
                for (int fn = 0; fn < FN; ++fn)
                    acc[fm][fn] = __builtin_amdgcn_mfma_f32_16x16x32_f16(
                        a[kk][fm], b[kk][fn], acc[fm][fn], 0, 0, 0);
        __syncthreads();
    }

    #pragma unroll
    for (int fm = 0; fm < 4; ++fm) {
        #pragma unroll
        for (int fn = 0; fn < FN; ++fn) {
            #pragma unroll
            for (int r = 0; r < 4; ++r) {
                int gr = row0 + wr * 64 + fm * 16 + (lane >> 4) * 4 + r;
                int gc = col0 + wc * WN + fn * 16 + (lane & 15);
                if (gr < M && gc < N) {
                    float v = acc[fm][fn][r];
                    if (bias) v += bias[gc];
                    if (outH) outH[(size_t)gr * N + gc] = (_Float16)v;
                    if (outF) outF[(size_t)gr * N + gc] = v;
                }
            }
        }
    }
}

// ---------------------------------------------------------------- SpMM D=256 f16, fused bias+relu+residual
// out[r] = f16( relu(sum_e v*Y[src] + bias) + res[r] )

__global__ __launch_bounds__(256) void spmm_epi_f16(const int* __restrict__ rowptr,
                                                    const int2* __restrict__ cev,
                                                    const _Float16* __restrict__ Y,
                                                    const float* __restrict__ bias,
                                                    const _Float16* __restrict__ res,
                                                    _Float16* __restrict__ out) {
    int row = (blockIdx.x * blockDim.x + threadIdx.x) >> 6;
    if (row >= N_NODES) return;
    int lane = threadIdx.x & 63;
    int col = lane * 4;
    int beg = rowptr[row];
    int end = rowptr[row + 1];
    float ax = 0.f, ay = 0.f, az = 0.f, aw = 0.f;
    for (int e = beg; e < end; ++e) {
        int2 ev = cev[e];
        float v = __int_as_float(ev.y);
        half4v h = *(const half4v*)(Y + (size_t)ev.x * NHID + col);
        ax = fmaf(v, (float)h[0], ax);
        ay = fmaf(v, (float)h[1], ay);
        az = fmaf(v, (float)h[2], az);
        aw = fmaf(v, (float)h[3], aw);
    }
    float4 bb = *(const float4*)(bias + col);
    half4v rr = *(const half4v*)(res + (size_t)row * NHID + col);
    half4v o;
    o[0] = (_Float16)(fmaxf(ax + bb.x, 0.f) + (float)rr[0]);
    o[1] = (_Float16)(fmaxf(ay + bb.y, 0.f) + (float)rr[1]);
    o[2] = (_Float16)(fmaxf(az + bb.z, 0.f) + (float)rr[2]);
    o[3] = (_Float16)(fmaxf(aw + bb.w, 0.f) + (float)rr[3]);
    *(half4v*)(out + (size_t)row * NHID + col) = o;
}

// ---------------------------------------------------------------- SpMM D=40 + bias + log_softmax

__global__ __launch_bounds__(256) void spmm40_lsm(const int* __restrict__ rowptr,
                                                  const int2* __restrict__ cev,
                                                  const float* __restrict__ Y,
                                                  const float* __restrict__ bias,
                                                  float* __restrict__ out) {
    int row = (blockIdx.x * blockDim.x + threadIdx.x) >> 6;
    if (row >= N_NODES) return;
    int lane = threadIdx.x & 63;
    bool act = lane < NCLASS;
    int beg = rowptr[row];
    int end = rowptr[row + 1];
    float acc = 0.f;
    for (int e = beg; e < end; ++e) {
        int2 ev = cev[e];
        float v = __int_as_float(ev.y);
        float h = act ? Y[(size_t)ev.x * NCLASS + lane] : 0.f;
        acc = fmaf(v, h, acc);
    }
    float x = act ? (acc + bias[lane]) : -INFINITY;
    float m = x;
    #pragma unroll
    for (int off = 32; off > 0; off >>= 1) m = fmaxf(m, __shfl_xor(m, off));
    float ex = act ? __expf(x - m) : 0.f;
    float ssum = ex;
    #pragma unroll
    for (int off = 32; off > 0; off >>= 1) ssum += __shfl_xor(ssum, off);
    float ls = logf(ssum);
    if (act) out[(size_t)row * NCLASS + lane] = x - m - ls;
}

// ---------------------------------------------------------------- launch

extern "C" void kernel_launch(void* const* d_in, const int* in_sizes, int n_in,
                              void* d_out, int out_size, void* d_ws, size_t ws_size,
                              hipStream_t stream) {
    const float* x     = (const float*)d_in[0];
    const int*   esrc  = (const int*)d_in[1];
    const int*   edst  = (const int*)d_in[2];
    const float* evals = (const float*)d_in[3];
    const float* W0 = (const float*)d_in[4];
    const float* b0 = (const float*)d_in[5];
    const float* W1 = (const float*)d_in[6];
    const float* b1 = (const float*)d_in[7];
    const float* W2 = (const float*)d_in[8];
    const float* b2 = (const float*)d_in[9];
    const float* W3 = (const float*)d_in[10];
    const float* b3 = (const float*)d_in[11];
    const float* W5 = (const float*)d_in[12];
    const float* b5 = (const float*)d_in[13];
    float* out = (float*)d_out;

    char* ws = (char*)d_ws;
    size_t off = 0;
    auto alloc = [&](size_t bytes) {
        char* p = ws + off;
        off = (off + bytes + 255) & ~(size_t)255;
        return p;
    };
    _Float16* xh  = (_Float16*)alloc(2ull * MPAD * NFEAT);
    _Float16* zh  = (_Float16*)alloc(2ull * N_NODES * NHID);
    _Float16* Yh  = (_Float16*)alloc(2ull * N_NODES * NHID);
    _Float16* x1h = (_Float16*)alloc(2ull * MPAD * NHID);
    _Float16* x2h = (_Float16*)alloc(2ull * MPAD * NHID);
    _Float16* x3h = (_Float16*)alloc(2ull * MPAD * NHID);
    _Float16* x4h = (_Float16*)alloc(2ull * MPAD * NHID);
    float*    Y5  = (float*)alloc(4ull * N_NODES * NCLASS);
    _Float16* BT0 = (_Float16*)alloc(2ull * NHID * NFEAT);
    _Float16* BT1 = (_Float16*)alloc(2ull * NHID * NFEAT);
    _Float16* BT2 = (_Float16*)alloc(2ull * NHID * NHID);
    _Float16* BT3 = (_Float16*)alloc(2ull * NHID * NHID);
    _Float16* BT5 = (_Float16*)alloc(2ull * 64 * 1024);
    int* cnt    = (int*)alloc(sizeof(int) * N_NODES);
    int* rowptr = (int*)alloc(sizeof(int) * (N_NODES + 1));
    int* cursor = (int*)alloc(sizeof(int) * N_NODES);
    int2* cev   = (int2*)alloc(8ull * N_EDGES);
    (void)ws_size;

    // ---- CSR build (by dst)
    zero_i32<<<(N_NODES + 255) / 256, 256, 0, stream>>>(cnt, N_NODES);
    hist_kernel<<<2048, 256, 0, stream>>>(edst, cnt, N_EDGES);
    exscan_kernel<<<1, 1024, 0, stream>>>(cnt, rowptr, cursor, N_NODES);
    scatter_kernel<<<2048, 256, 0, stream>>>(esrc, edst, evals, cursor, cev, N_EDGES);

    // ---- conversions
    conv_x_kernel<<<(N_NODES * NFEAT / 8 + 255) / 256, 256, 0, stream>>>(x, xh, N_NODES * NFEAT / 8);
    conv_w_kernel<<<(NHID * NFEAT + 255) / 256, 256, 0, stream>>>(W0, BT0, NFEAT, NHID, NHID);
    conv_w_kernel<<<(NHID * NFEAT + 255) / 256, 256, 0, stream>>>(W1, BT1, NFEAT, NHID, NHID);
    conv_w_kernel<<<(NHID * NHID + 255) / 256, 256, 0, stream>>>(W2, BT2, NHID, NHID, NHID);
    conv_w_kernel<<<(NHID * NHID + 255) / 256, 256, 0, stream>>>(W3, BT3, NHID, NHID, NHID);
    conv_w_kernel<<<(64 * 1024 + 255) / 256, 256, 0, stream>>>(W5, BT5, 1024, NCLASS, 64);

    const int mtiles = MPAD / 128;  // 391
    dim3 blk(256);
    dim3 gBig(NHID / 128, mtiles);

    // z = x@W0 + b0 -> zh
    gemm_f16<128><<<gBig, blk, 0, stream>>>(xh, xh, xh, xh, NFEAT, NFEAT, BT0, b0, zh, nullptr, N_NODES, NHID);
    // y1 = x@W1 -> Yh ; x1 = relu(spmm+b1) + z
    gemm_f16<128><<<gBig, blk, 0, stream>>>(xh, xh, xh, xh, NFEAT, NFEAT, BT1, nullptr, Yh, nullptr, N_NODES, NHID);
    spmm_epi_f16<<<(N_NODES * 64) / 256, blk, 0, stream>>>(rowptr, cev, Yh, b1, zh, x1h);

    // layer 2
    gemm_f16<128><<<gBig, blk, 0, stream>>>(x1h, x1h, x1h, x1h, NHID, NHID, BT2, nullptr, Yh, nullptr, N_NODES, NHID);
    spmm_epi_f16<<<(N_NODES * 64) / 256, blk, 0, stream>>>(rowptr, cev, Yh, b2, x1h, x2h);

    // layer 3 (same W2/b2)
    gemm_f16<128><<<gBig, blk, 0, stream>>>(x2h, x2h, x2h, x2h, NHID, NHID, BT2, nullptr, Yh, nullptr, N_NODES, NHID);
    spmm_epi_f16<<<(N_NODES * 64) / 256, blk, 0, stream>>>(rowptr, cev, Yh, b2, x2h, x3h);

    // layer 4
    gemm_f16<128><<<gBig, blk, 0, stream>>>(x3h, x3h, x3h, x3h, NHID, NHID, BT3, nullptr, Yh, nullptr, N_NODES, NHID);
    spmm_epi_f16<<<(N_NODES * 64) / 256, blk, 0, stream>>>(rowptr, cev, Yh, b3, x3h, x4h);

    // Y5 = concat(x4,x3,x2,x1) @ W5   (single kernel, K-concat of 4 parts)
    gemm_f16<64><<<dim3(1, mtiles), blk, 0, stream>>>(x4h, x3h, x2h, x1h, NHID, 4 * NHID, BT5,
                                                      nullptr, nullptr, Y5, N_NODES, NCLASS);

    // out = log_softmax(spmm(Y5) + b5)
    spmm40_lsm<<<(N_NODES * 64) / 256, blk, 0, stream>>>(rowptr, cev, Y5, b5, out);
}

// Round 3
// 922.266 us; speedup vs baseline: 2.3431x; 1.3783x over previous
//
#include <hip/hip_runtime.h>
#include <math.h>
#include <stdint.h>

#define N_NODES 50000
#define N_EDGES 1600000
#define NFEAT 512
#define NHID 256
#define NCLASS 40
#define MPAD 50048  // 391 * 128

typedef _Float16 half8 __attribute__((ext_vector_type(8)));
typedef _Float16 half4v __attribute__((ext_vector_type(4)));
typedef float floatx4 __attribute__((ext_vector_type(4)));

__device__ __forceinline__ void gload_lds16(const void* g, void* l) {
    __builtin_amdgcn_global_load_lds((const __attribute__((address_space(1))) void*)g,
                                     (__attribute__((address_space(3))) void*)l, 16, 0, 0);
}

// ---------------------------------------------------------------- CSR build

__global__ void zero_i32(int* __restrict__ p, int n) {
    int i = blockIdx.x * blockDim.x + threadIdx.x;
    if (i < n) p[i] = 0;
}

__global__ void hist_kernel(const int* __restrict__ dst, int* __restrict__ cnt, int n) {
    int i = blockIdx.x * blockDim.x + threadIdx.x;
    int stride = gridDim.x * blockDim.x;
    for (; i < n; i += stride) atomicAdd(&cnt[dst[i]], 1);
}

// exclusive scan, 1 block, 4 elems/thread, shfl-based (few barriers)
__global__ __launch_bounds__(1024) void exscan4_kernel(const int* __restrict__ cnt,
                                                       int* __restrict__ rowptr,
                                                       int* __restrict__ cursor, int n) {
    __shared__ int wsum[16];
    __shared__ int carry_s;
    const int tid = threadIdx.x;
    const int lane = tid & 63;
    const int wid = tid >> 6;
    if (tid == 0) carry_s = 0;
    __syncthreads();
    for (int base = 0; base < n; base += 4096) {
        int i0 = base + tid * 4;
        int4 v = make_int4(0, 0, 0, 0);
        if (i0 + 3 < n) {
            v = *(const int4*)(cnt + i0);
        } else {
            if (i0 + 0 < n) v.x = cnt[i0 + 0];
            if (i0 + 1 < n) v.y = cnt[i0 + 1];
            if (i0 + 2 < n) v.z = cnt[i0 + 2];
        }
        int s = v.x + v.y + v.z + v.w;
        int sc = s;
        #pragma unroll
        for (int off = 1; off < 64; off <<= 1) {
            int t = __shfl_up(sc, off);
            if (lane >= off) sc += t;
        }
        if (lane == 63) wsum[wid] = sc;
        __syncthreads();
        if (wid == 0) {
            int ws = (lane < 16) ? wsum[lane] : 0;
            #pragma unroll
            for (int off = 1; off < 16; off <<= 1) {
                int t = __shfl_up(ws, off);
                if (lane >= off) ws += t;
            }
            if (lane < 16) wsum[lane] = ws;
        }
        __syncthreads();
        int ex = carry_s + (wid ? wsum[wid - 1] : 0) + sc - s;
        int p0 = ex, p1 = ex + v.x, p2 = p1 + v.y, p3 = p2 + v.z;
        if (i0 + 0 < n) { rowptr[i0 + 0] = p0; cursor[i0 + 0] = p0; }
        if (i0 + 1 < n) { rowptr[i0 + 1] = p1; cursor[i0 + 1] = p1; }
        if (i0 + 2 < n) { rowptr[i0 + 2] = p2; cursor[i0 + 2] = p2; }
        if (i0 + 3 < n) { rowptr[i0 + 3] = p3; cursor[i0 + 3] = p3; }
        __syncthreads();
        if (tid == 0) carry_s += wsum[15];
        __syncthreads();
    }
    if (tid == 0) rowptr[n] = carry_s;
}

__global__ void scatter_kernel(const int* __restrict__ src, const int* __restrict__ dst,
                               const float* __restrict__ vals, int* __restrict__ cursor,
                               int2* __restrict__ cev, int n) {
    int i = blockIdx.x * blockDim.x + threadIdx.x;
    int stride = gridDim.x * blockDim.x;
    for (; i < n; i += stride) {
        int d = dst[i];
        int p = atomicAdd(&cursor[d], 1);
        cev[p] = make_int2(src[i], __float_as_int(vals[i]));
    }
}

// ---------------------------------------------------------------- conversions

__global__ void conv_x_kernel(const float* __restrict__ x, _Float16* __restrict__ xh, int total8) {
    int id = blockIdx.x * blockDim.x + threadIdx.x;
    if (id >= total8) return;
    const float4* p = (const float4*)x + (size_t)id * 2;
    float4 a = p[0], b = p[1];
    half8 h;
    h[0] = (_Float16)a.x; h[1] = (_Float16)a.y; h[2] = (_Float16)a.z; h[3] = (_Float16)a.w;
    h[4] = (_Float16)b.x; h[5] = (_Float16)b.y; h[6] = (_Float16)b.z; h[7] = (_Float16)b.w;
    *((half8*)xh + id) = h;
}

// W [K][N] f32 -> BT [Npad][K] f16 (transposed, zero-padded rows)
__global__ void conv_w_kernel(const float* __restrict__ W, _Float16* __restrict__ BT,
                              int K, int N, int Npad) {
    int id = blockIdx.x * blockDim.x + threadIdx.x;
    if (id >= Npad * K) return;
    int n = id / K;
    int k = id - n * K;
    BT[id] = (n < N) ? (_Float16)W[(size_t)k * N + n] : (_Float16)0.f;
}

// ---------------------------------------------------------------- f16 MFMA GEMM
// C[M,N] = A[M,K] * BT[N,K]^T ; A may be split into up to 4 row-major parts of
// kPerPart columns each (K-concat). Column-split f16 outputs with per-part bias.

template<int BN>
__global__ __launch_bounds__(256, 2)
void gemm_f16(const _Float16* __restrict__ A0, const _Float16* __restrict__ A1,
              const _Float16* __restrict__ A2, const _Float16* __restrict__ A3,
              int kPerPart, int K,
              const _Float16* __restrict__ BT,
              const float* __restrict__ bias1, _Float16* __restrict__ out1,
              const float* __restrict__ bias2, _Float16* __restrict__ out2,
              int splitN, int M, int N) {
    constexpr int WN = BN / 2;
    constexpr int FN = WN / 16;
    __shared__ _Float16 As[128 * 64];
    __shared__ _Float16 Bs[BN * 64];

    const int tid = threadIdx.x;
    const int w = tid >> 6;
    const int lane = tid & 63;
    const int row0 = blockIdx.y * 128;
    const int col0 = blockIdx.x * BN;

    const int wr = w >> 1;
    const int wc = w & 1;
    const int mi = lane & 15;
    const int ksel = lane >> 4;

    // staging constants: lane -> (row-in-8, swizzled source col in elems)
    const int srow = lane >> 3;
    const int scol = ((lane & 7) ^ srow) << 3;

    floatx4 acc[4][FN];
    #pragma unroll
    for (int i = 0; i < 4; ++i)
        #pragma unroll
        for (int j = 0; j < FN; ++j)
            acc[i][j] = (floatx4)0.f;

    for (int k0 = 0; k0 < K; k0 += 64) {
        int part = k0 / kPerPart;
        int kloc = k0 - part * kPerPart;
        const _Float16* Ap = (part == 0) ? A0 : (part == 1) ? A1 : (part == 2) ? A2 : A3;

        // stage A tile: 128 rows x 64 f16 (row = 128B), 16 wave-issues of 1KB
        #pragma unroll
        for (int j = 0; j < 4; ++j) {
            int rowblk = (j * 4 + w) * 8;
            const _Float16* src = Ap + (size_t)(row0 + rowblk + srow) * kPerPart + kloc + scol;
            gload_lds16(src, (char*)As + rowblk * 128);
        }
        // stage B tile: BN rows x 64 f16
        #pragma unroll
        for (int j = 0; j < BN / 32; ++j) {
            int nblk = (j * 4 + w) * 8;
            const _Float16* src = BT + (size_t)(col0 + nblk + srow) * K + k0 + scol;
            gload_lds16(src, (char*)Bs + nblk * 128);
        }
        asm volatile("s_waitcnt vmcnt(0)" ::: "memory");
        __syncthreads();

        half8 a[2][4];
        half8 b[2][FN];
        #pragma unroll
        for (int kk = 0; kk < 2; ++kk) {
            int kb = kk * 64 + (ksel << 4);
            #pragma unroll
            for (int fm = 0; fm < 4; ++fm) {
                int r = wr * 64 + fm * 16 + mi;
                int byte = kb ^ ((r & 7) << 4);
                a[kk][fm] = *(const half8*)((const char*)As + r * 128 + byte);
            }
            #pragma unroll
            for (int fn = 0; fn < FN; ++fn) {
                int n = wc * WN + fn * 16 + mi;
                int byte = kb ^ ((n & 7) << 4);
                b[kk][fn] = *(const half8*)((const char*)Bs + n * 128 + byte);
            }
        }
        #pragma unroll
        for (int kk = 0; kk < 2; ++kk)
            #pragma unroll
            for (int fm = 0; fm < 4; ++fm)
                #pragma unroll
                for (int fn = 0; fn < FN; ++fn)
                    acc[fm][fn] = __builtin_amdgcn_mfma_f32_16x16x32_f16(
                        a[kk][fm], b[kk][fn], acc[fm][fn], 0, 0, 0);
        __syncthreads();
    }

    #pragma unroll
    for (int fm = 0; fm < 4; ++fm) {
        #pragma unroll
        for (int fn = 0; fn < FN; ++fn) {
            #pragma unroll
            for (int r = 0; r < 4; ++r) {
                int gr = row0 + wr * 64 + fm * 16 + (lane >> 4) * 4 + r;
                int gc = col0 + wc * WN + fn * 16 + (lane & 15);
                if (gr < M && gc < N) {
                    float v = acc[fm][fn][r];
                    if (out2 && gc >= splitN) {
                        if (bias2) v += bias2[gc - splitN];
                        out2[(size_t)gr * (N - splitN) + (gc - splitN)] = (_Float16)v;
                    } else {
                        if (bias1) v += bias1[gc];
                        int strideO = out2 ? splitN : N;
                        out1[(size_t)gr * strideO + gc] = (_Float16)v;
                    }
                }
            }
        }
    }
}

// ---------------------------------------------------------------- SpMM D=256 f16, fused bias+relu+residual
// out[r] = f16( relu(sum_e v*Y[src] + bias) + res[r] ); 8-deep MLP unroll

__global__ __launch_bounds__(256) void spmm_epi_f16(const int* __restrict__ rowptr,
                                                    const int2* __restrict__ cev,
                                                    const _Float16* __restrict__ Y,
                                                    const float* __restrict__ bias,
                                                    const _Float16* __restrict__ res,
                                                    _Float16* __restrict__ out) {
    int row = (blockIdx.x * blockDim.x + threadIdx.x) >> 6;
    if (row >= N_NODES) return;
    int lane = threadIdx.x & 63;
    int col = lane * 4;
    const _Float16* Ycol = Y + col;
    int beg = rowptr[row];
    int end = rowptr[row + 1];
    float a0 = 0.f, a1 = 0.f, a2 = 0.f, a3 = 0.f;
    int e = beg;
    for (; e + 8 <= end; e += 8) {
        int2 ev[8];
        #pragma unroll
        for (int j = 0; j < 8; ++j) ev[j] = cev[e + j];
        half4v h[8];
        #pragma unroll
        for (int j = 0; j < 8; ++j) h[j] = *(const half4v*)(Ycol + (size_t)ev[j].x * NHID);
        #pragma unroll
        for (int j = 0; j < 8; ++j) {
            float v = __int_as_float(ev[j].y);
            a0 = fmaf(v, (float)h[j][0], a0);
            a1 = fmaf(v, (float)h[j][1], a1);
            a2 = fmaf(v, (float)h[j][2], a2);
            a3 = fmaf(v, (float)h[j][3], a3);
        }
    }
    for (; e < end; ++e) {
        int2 ev = cev[e];
        float v = __int_as_float(ev.y);
        half4v h = *(const half4v*)(Ycol + (size_t)ev.x * NHID);
        a0 = fmaf(v, (float)h[0], a0);
        a1 = fmaf(v, (float)h[1], a1);
        a2 = fmaf(v, (float)h[2], a2);
        a3 = fmaf(v, (float)h[3], a3);
    }
    float4 bb = *(const float4*)(bias + col);
    half4v rr = *(const half4v*)(res + (size_t)row * NHID + col);
    half4v o;
    o[0] = (_Float16)(fmaxf(a0 + bb.x, 0.f) + (float)rr[0]);
    o[1] = (_Float16)(fmaxf(a1 + bb.y, 0.f) + (float)rr[1]);
    o[2] = (_Float16)(fmaxf(a2 + bb.z, 0.f) + (float)rr[2]);
    o[3] = (_Float16)(fmaxf(a3 + bb.w, 0.f) + (float)rr[3]);
    *(half4v*)(out + (size_t)row * NHID + col) = o;
}

// ---------------------------------------------------------------- SpMM D=40 (f16 Y) + bias + log_softmax

__global__ __launch_bounds__(256) void spmm40_lsm(const int* __restrict__ rowptr,
                                                  const int2* __restrict__ cev,
                                                  const _Float16* __restrict__ Y5,
                                                  const float* __restrict__ bias,
                                                  float* __restrict__ out) {
    int row = (blockIdx.x * blockDim.x + threadIdx.x) >> 6;
    if (row >= N_NODES) return;
    int lane = threadIdx.x & 63;
    bool act = lane < NCLASS;
    const _Float16* Yl = Y5 + lane;
    int beg = rowptr[row];
    int end = rowptr[row + 1];
    float acc = 0.f;
    int e = beg;
    for (; e + 8 <= end; e += 8) {
        int2 ev[8];
        #pragma unroll
        for (int j = 0; j < 8; ++j) ev[j] = cev[e + j];
        float h[8];
        #pragma unroll
        for (int j = 0; j < 8; ++j) h[j] = act ? (float)Yl[(size_t)ev[j].x * NCLASS] : 0.f;
        #pragma unroll
        for (int j = 0; j < 8; ++j) acc = fmaf(__int_as_float(ev[j].y), h[j], acc);
    }
    for (; e < end; ++e) {
        int2 ev = cev[e];
        float h = act ? (float)Yl[(size_t)ev.x * NCLASS] : 0.f;
        acc = fmaf(__int_as_float(ev.y), h, acc);
    }
    float x = act ? (acc + bias[lane]) : -INFINITY;
    float m = x;
    #pragma unroll
    for (int off = 32; off > 0; off >>= 1) m = fmaxf(m, __shfl_xor(m, off));
    float ex = act ? __expf(x - m) : 0.f;
    float ssum = ex;
    #pragma unroll
    for (int off = 32; off > 0; off >>= 1) ssum += __shfl_xor(ssum, off);
    float ls = logf(ssum);
    if (act) out[(size_t)row * NCLASS + lane] = x - m - ls;
}

// ---------------------------------------------------------------- launch

extern "C" void kernel_launch(void* const* d_in, const int* in_sizes, int n_in,
                              void* d_out, int out_size, void* d_ws, size_t ws_size,
                              hipStream_t stream) {
    const float* x     = (const float*)d_in[0];
    const int*   esrc  = (const int*)d_in[1];
    const int*   edst  = (const int*)d_in[2];
    const float* evals = (const float*)d_in[3];
    const float* W0 = (const float*)d_in[4];
    const float* b0 = (const float*)d_in[5];
    const float* W1 = (const float*)d_in[6];
    const float* b1 = (const float*)d_in[7];
    const float* W2 = (const float*)d_in[8];
    const float* b2 = (const float*)d_in[9];
    const float* W3 = (const float*)d_in[10];
    const float* b3 = (const float*)d_in[11];
    const float* W5 = (const float*)d_in[12];
    const float* b5 = (const float*)d_in[13];
    float* out = (float*)d_out;

    char* ws = (char*)d_ws;
    size_t off = 0;
    auto alloc = [&](size_t bytes) {
        char* p = ws + off;
        off = (off + bytes + 255) & ~(size_t)255;
        return p;
    };
    _Float16* xh   = (_Float16*)alloc(2ull * MPAD * NFEAT);
    _Float16* zh   = (_Float16*)alloc(2ull * N_NODES * NHID);
    _Float16* Yh   = (_Float16*)alloc(2ull * N_NODES * NHID);
    _Float16* x1h  = (_Float16*)alloc(2ull * MPAD * NHID);
    _Float16* x2h  = (_Float16*)alloc(2ull * MPAD * NHID);
    _Float16* x3h  = (_Float16*)alloc(2ull * MPAD * NHID);
    _Float16* x4h  = (_Float16*)alloc(2ull * MPAD * NHID);
    _Float16* Y5h  = (_Float16*)alloc(2ull * N_NODES * NCLASS);
    _Float16* BT01 = (_Float16*)alloc(2ull * 512 * NFEAT);
    _Float16* BT2  = (_Float16*)alloc(2ull * NHID * NHID);
    _Float16* BT3  = (_Float16*)alloc(2ull * NHID * NHID);
    _Float16* BT5  = (_Float16*)alloc(2ull * 64 * 1024);
    int* cnt    = (int*)alloc(sizeof(int) * N_NODES);
    int* rowptr = (int*)alloc(sizeof(int) * (N_NODES + 1));
    int* cursor = (int*)alloc(sizeof(int) * N_NODES);
    int2* cev   = (int2*)alloc(8ull * N_EDGES);
    (void)ws_size;

    // ---- CSR build (by dst)
    zero_i32<<<(N_NODES + 255) / 256, 256, 0, stream>>>(cnt, N_NODES);
    hist_kernel<<<2048, 256, 0, stream>>>(edst, cnt, N_EDGES);
    exscan4_kernel<<<1, 1024, 0, stream>>>(cnt, rowptr, cursor, N_NODES);
    scatter_kernel<<<2048, 256, 0, stream>>>(esrc, edst, evals, cursor, cev, N_EDGES);

    // ---- conversions
    conv_x_kernel<<<(N_NODES * NFEAT / 8 + 255) / 256, 256, 0, stream>>>(x, xh, N_NODES * NFEAT / 8);
    conv_w_kernel<<<(256 * NFEAT + 255) / 256, 256, 0, stream>>>(W0, BT01, NFEAT, NHID, NHID);
    conv_w_kernel<<<(256 * NFEAT + 255) / 256, 256, 0, stream>>>(W1, BT01 + 256 * NFEAT, NFEAT, NHID, NHID);
    conv_w_kernel<<<(NHID * NHID + 255) / 256, 256, 0, stream>>>(W2, BT2, NHID, NHID, NHID);
    conv_w_kernel<<<(NHID * NHID + 255) / 256, 256, 0, stream>>>(W3, BT3, NHID, NHID, NHID);
    conv_w_kernel<<<(64 * 1024 + 255) / 256, 256, 0, stream>>>(W5, BT5, 1024, NCLASS, 64);

    const int mtiles = MPAD / 128;  // 391
    dim3 blk(256);

    // fused: [z | y1] = x @ [W0 | W1]  (N=512, split at 256)
    gemm_f16<128><<<dim3(4, mtiles), blk, 0, stream>>>(xh, xh, xh, xh, NFEAT, NFEAT, BT01,
                                                       b0, zh, nullptr, Yh, 256, N_NODES, 512);
    // x1 = relu(spmm(y1)+b1) + z
    spmm_epi_f16<<<(N_NODES * 64) / 256, blk, 0, stream>>>(rowptr, cev, Yh, b1, zh, x1h);

    // layer 2
    gemm_f16<128><<<dim3(2, mtiles), blk, 0, stream>>>(x1h, x1h, x1h, x1h, NHID, NHID, BT2,
                                                       nullptr, Yh, nullptr, nullptr, 0, N_NODES, NHID);
    spmm_epi_f16<<<(N_NODES * 64) / 256, blk, 0, stream>>>(rowptr, cev, Yh, b2, x1h, x2h);

    // layer 3 (same W2/b2)
    gemm_f16<128><<<dim3(2, mtiles), blk, 0, stream>>>(x2h, x2h, x2h, x2h, NHID, NHID, BT2,
                                                       nullptr, Yh, nullptr, nullptr, 0, N_NODES, NHID);
    spmm_epi_f16<<<(N_NODES * 64) / 256, blk, 0, stream>>>(rowptr, cev, Yh, b2, x2h, x3h);

    // layer 4
    gemm_f16<128><<<dim3(2, mtiles), blk, 0, stream>>>(x3h, x3h, x3h, x3h, NHID, NHID, BT3,
                                                       nullptr, Yh, nullptr, nullptr, 0, N_NODES, NHID);
    spmm_epi_f16<<<(N_NODES * 64) / 256, blk, 0, stream>>>(rowptr, cev, Yh, b3, x3h, x4h);

    // Y5 = concat(x4,x3,x2,x1) @ W5  (K-concat of 4 parts, f16 out)
    gemm_f16<64><<<dim3(1, mtiles), blk, 0, stream>>>(x4h, x3h, x2h, x1h, NHID, 4 * NHID, BT5,
                                                      nullptr, Y5h, nullptr, nullptr, 0, N_NODES, NCLASS);

    // out = log_softmax(spmm(Y5) + b5)
    spmm40_lsm<<<(N_NODES * 64) / 256, blk, 0, stream>>>(rowptr, cev, Y5h, b5, out);
}

// Round 4
// 880.121 us; speedup vs baseline: 2.4553x; 1.0479x over previous
//
#include <hip/hip_runtime.h>
#include <math.h>
#include <stdint.h>

#define N_NODES 50000
#define N_EDGES 1600000
#define NFEAT 512
#define NHID 256
#define NCLASS 40
#define MPAD 50048        // 391 * 128
#define NPART 8
#define ROWS_PER_PART 6250
#define PCAP 212992       // >> 200K mean + 31 sigma
#define EPB 4096          // edges per block in bin pass
#define BPP 128           // blocks per partition in scatter pass

typedef _Float16 half8 __attribute__((ext_vector_type(8)));
typedef _Float16 half4v __attribute__((ext_vector_type(4)));
typedef float floatx4 __attribute__((ext_vector_type(4)));

__device__ __forceinline__ void gload_lds16(const void* g, void* l) {
    __builtin_amdgcn_global_load_lds((const __attribute__((address_space(1))) void*)g,
                                     (__attribute__((address_space(3))) void*)l, 16, 0, 0);
}

__device__ __forceinline__ float cev_val(unsigned ev) {
    return (float)__builtin_bit_cast(_Float16, (unsigned short)(ev >> 16));
}

// ---------------------------------------------------------------- CSR build

__global__ void zero_i32(int* __restrict__ p, int n) {
    int i = blockIdx.x * blockDim.x + threadIdx.x;
    if (i < n) p[i] = 0;
}

// Pass A: bin edges into NPART dst-range partitions + global per-row histogram.
__global__ __launch_bounds__(256) void bin_kernel(const int* __restrict__ esrc,
                                                  const int* __restrict__ edst,
                                                  const float* __restrict__ evals,
                                                  int* __restrict__ cnt,
                                                  int* __restrict__ pcount,
                                                  uint2* __restrict__ plist) {
    __shared__ int lcnt[NPART], lbase[NPART], lcur[NPART];
    int base = blockIdx.x * EPB;
    int n = min(EPB, N_EDGES - base);
    if (threadIdx.x < NPART) lcnt[threadIdx.x] = 0;
    __syncthreads();
    for (int i = threadIdx.x; i < n; i += 256) {
        int d = edst[base + i];
        atomicAdd(&lcnt[d / ROWS_PER_PART], 1);
        atomicAdd(&cnt[d], 1);
    }
    __syncthreads();
    if (threadIdx.x < NPART) {
        lbase[threadIdx.x] = atomicAdd(&pcount[threadIdx.x], lcnt[threadIdx.x]);
        lcur[threadIdx.x] = 0;
    }
    __syncthreads();
    for (int i = threadIdx.x; i < n; i += 256) {
        int d = edst[base + i];
        int p = d / ROWS_PER_PART;
        int o = atomicAdd(&lcur[p], 1);
        int s = esrc[base + i];
        plist[(size_t)p * PCAP + lbase[p] + o] =
            make_uint2((unsigned)((d << 16) | s), __float_as_uint(evals[base + i]));
    }
}

// exclusive scan, 1 block, 4 elems/thread, shfl-based
__global__ __launch_bounds__(1024) void exscan4_kernel(const int* __restrict__ cnt,
                                                       int* __restrict__ rowptr,
                                                       int* __restrict__ cursor, int n) {
    __shared__ int wsum[16];
    __shared__ int carry_s;
    const int tid = threadIdx.x;
    const int lane = tid & 63;
    const int wid = tid >> 6;
    if (tid == 0) carry_s = 0;
    __syncthreads();
    for (int base = 0; base < n; base += 4096) {
        int i0 = base + tid * 4;
        int4 v = make_int4(0, 0, 0, 0);
        if (i0 + 3 < n) {
            v = *(const int4*)(cnt + i0);
        } else {
            if (i0 + 0 < n) v.x = cnt[i0 + 0];
            if (i0 + 1 < n) v.y = cnt[i0 + 1];
            if (i0 + 2 < n) v.z = cnt[i0 + 2];
        }
        int s = v.x + v.y + v.z + v.w;
        int sc = s;
        #pragma unroll
        for (int off = 1; off < 64; off <<= 1) {
            int t = __shfl_up(sc, off);
            if (lane >= off) sc += t;
        }
        if (lane == 63) wsum[wid] = sc;
        __syncthreads();
        if (wid == 0) {
            int ws = (lane < 16) ? wsum[lane] : 0;
            #pragma unroll
            for (int off = 1; off < 16; off <<= 1) {
                int t = __shfl_up(ws, off);
                if (lane >= off) ws += t;
            }
            if (lane < 16) wsum[lane] = ws;
        }
        __syncthreads();
        int ex = carry_s + (wid ? wsum[wid - 1] : 0) + sc - s;
        int p0 = ex, p1 = ex + v.x, p2 = p1 + v.y, p3 = p2 + v.z;
        if (i0 + 0 < n) { rowptr[i0 + 0] = p0; cursor[i0 + 0] = p0; }
        if (i0 + 1 < n) { rowptr[i0 + 1] = p1; cursor[i0 + 1] = p1; }
        if (i0 + 2 < n) { rowptr[i0 + 2] = p2; cursor[i0 + 2] = p2; }
        if (i0 + 3 < n) { rowptr[i0 + 3] = p3; cursor[i0 + 3] = p3; }
        __syncthreads();
        if (tid == 0) carry_s += wsum[15];
        __syncthreads();
    }
    if (tid == 0) rowptr[n] = carry_s;
}

// Pass B: per-partition scatter; partition = blockIdx % 8 matches XCD round-robin,
// so each XCD's atomics+writes stay in its own ~800KB cev region (L2-combining).
__global__ __launch_bounds__(256) void pscatter_kernel(const int* __restrict__ pcount,
                                                       const uint2* __restrict__ plist,
                                                       int* __restrict__ cursor,
                                                       unsigned* __restrict__ cev) {
    int part = blockIdx.x & (NPART - 1);
    int bip = blockIdx.x >> 3;
    int n = pcount[part];
    const uint2* lp = plist + (size_t)part * PCAP;
    for (int i = bip * 256 + threadIdx.x; i < n; i += BPP * 256) {
        uint2 r = lp[i];
        int d = r.x >> 16;
        int s = r.x & 0xFFFF;
        int pos = atomicAdd(&cursor[d], 1);
        unsigned short hb = __builtin_bit_cast(unsigned short, (_Float16)__uint_as_float(r.y));
        cev[pos] = ((unsigned)hb << 16) | (unsigned)s;
    }
}

// ---------------------------------------------------------------- conversions

// W [K][N] f32 -> BT [Npad][K] f16 (transposed, zero-padded rows)
__global__ void conv_w_kernel(const float* __restrict__ W, _Float16* __restrict__ BT,
                              int K, int N, int Npad) {
    int id = blockIdx.x * blockDim.x + threadIdx.x;
    if (id >= Npad * K) return;
    int n = id / K;
    int k = id - n * K;
    BT[id] = (n < N) ? (_Float16)W[(size_t)k * N + n] : (_Float16)0.f;
}

// ---------------------------------------------------------------- GEMM #1: A = x (f32), N=512 col-split
// [z | y1] = x @ [W0|W1]^T ; out1 = zh (cols 0..255, +b0), out2 = Yh (cols 256..511)

__global__ __launch_bounds__(256, 2)
void gemm_xf32(const float* __restrict__ A, const _Float16* __restrict__ BT,
               const float* __restrict__ bias1,
               _Float16* __restrict__ out1, _Float16* __restrict__ out2) {
    __shared__ float As[128 * 64];       // 32 KB, row = 256B, granule-XOR swizzled
    __shared__ _Float16 Bs[128 * 64];    // 16 KB

    const int tid = threadIdx.x;
    const int w = tid >> 6;
    const int lane = tid & 63;
    const int row0 = blockIdx.y * 128;
    const int col0 = blockIdx.x * 128;

    const int wr = w >> 1;
    const int wc = w & 1;
    const int mi = lane & 15;
    const int ksel = lane >> 4;

    // B staging (f16 rows of 128B): 8 rows per 1KB issue
    const int srowB = lane >> 3;
    const int scolB = ((lane & 7) ^ srowB) << 3;
    // A staging (f32 rows of 256B): 4 rows per 1KB issue
    const int srA = lane >> 4;
    const int gA = lane & 15;

    floatx4 acc[4][4];
    #pragma unroll
    for (int i = 0; i < 4; ++i)
        #pragma unroll
        for (int j = 0; j < 4; ++j)
            acc[i][j] = (floatx4)0.f;

    for (int k0 = 0; k0 < NFEAT; k0 += 64) {
        // A tile: 128 rows x 64 f32
        #pragma unroll
        for (int j = 0; j < 8; ++j) {
            int chunk = j * 4 + w;           // 0..31
            int r = chunk * 4 + srA;         // 0..127
            int gr = min(row0 + r, N_NODES - 1);
            int gsw = gA ^ (r & 15);
            const float* src = A + (size_t)gr * NFEAT + k0 + gsw * 4;
            gload_lds16(src, (char*)As + chunk * 1024);
        }
        // B tile: 128 rows x 64 f16
        #pragma unroll
        for (int j = 0; j < 4; ++j) {
            int nblk = (j * 4 + w) * 8;
            const _Float16* src = BT + (size_t)(col0 + nblk + srowB) * NFEAT + k0 + scolB;
            gload_lds16(src, (char*)Bs + nblk * 128);
        }
        asm volatile("s_waitcnt vmcnt(0)" ::: "memory");
        __syncthreads();

        half8 a[2][4];
        half8 b[2][4];
        #pragma unroll
        for (int kk = 0; kk < 2; ++kk) {
            #pragma unroll
            for (int fm = 0; fm < 4; ++fm) {
                int r = wr * 64 + fm * 16 + mi;
                int g0 = (kk * 8 + ksel * 2 + 0) ^ (r & 15);
                int g1 = (kk * 8 + ksel * 2 + 1) ^ (r & 15);
                floatx4 f0 = *(const floatx4*)((const char*)As + r * 256 + g0 * 16);
                floatx4 f1 = *(const floatx4*)((const char*)As + r * 256 + g1 * 16);
                half8 av;
                av[0] = (_Float16)f0[0]; av[1] = (_Float16)f0[1];
                av[2] = (_Float16)f0[2]; av[3] = (_Float16)f0[3];
                av[4] = (_Float16)f1[0]; av[5] = (_Float16)f1[1];
                av[6] = (_Float16)f1[2]; av[7] = (_Float16)f1[3];
                a[kk][fm] = av;
            }
            int kb = kk * 64 + (ksel << 4);
            #pragma unroll
            for (int fn = 0; fn < 4; ++fn) {
                int n = wc * 64 + fn * 16 + mi;
                int byte = kb ^ ((n & 7) << 4);
                b[kk][fn] = *(const half8*)((const char*)Bs + n * 128 + byte);
            }
        }
        #pragma unroll
        for (int kk = 0; kk < 2; ++kk)
            #pragma unroll
            for (int fm = 0; fm < 4; ++fm)
                #pragma unroll
                for (int fn = 0; fn < 4; ++fn)
                    acc[fm][fn] = __builtin_amdgcn_mfma_f32_16x16x32_f16(
                        a[kk][fm], b[kk][fn], acc[fm][fn], 0, 0, 0);
        __syncthreads();
    }

    #pragma unroll
    for (int fm = 0; fm < 4; ++fm) {
        #pragma unroll
        for (int fn = 0; fn < 4; ++fn) {
            #pragma unroll
            for (int r = 0; r < 4; ++r) {
                int gr = row0 + wr * 64 + fm * 16 + (lane >> 4) * 4 + r;
                int gc = col0 + wc * 64 + fn * 16 + (lane & 15);
                if (gr < N_NODES) {
                    float v = acc[fm][fn][r];
                    if (gc < 256) {
                        out1[(size_t)gr * 256 + gc] = (_Float16)(v + bias1[gc]);
                    } else {
                        out2[(size_t)gr * 256 + (gc - 256)] = (_Float16)v;
                    }
                }
            }
        }
    }
}

// ---------------------------------------------------------------- f16 MFMA GEMM (A f16, K-concat up to 4)

template<int BN>
__global__ __launch_bounds__(256, 2)
void gemm_f16(const _Float16* __restrict__ A0, const _Float16* __restrict__ A1,
              const _Float16* __restrict__ A2, const _Float16* __restrict__ A3,
              int kPerPart, int K,
              const _Float16* __restrict__ BT,
              const float* __restrict__ bias1, _Float16* __restrict__ out1,
              int M, int N) {
    constexpr int WN = BN / 2;
    constexpr int FN = WN / 16;
    __shared__ _Float16 As[128 * 64];
    __shared__ _Float16 Bs[BN * 64];

    const int tid = threadIdx.x;
    const int w = tid >> 6;
    const int lane = tid & 63;
    const int row0 = blockIdx.y * 128;
    const int col0 = blockIdx.x * BN;

    const int wr = w >> 1;
    const int wc = w & 1;
    const int mi = lane & 15;
    const int ksel = lane >> 4;

    const int srow = lane >> 3;
    const int scol = ((lane & 7) ^ srow) << 3;

    floatx4 acc[4][FN];
    #pragma unroll
    for (int i = 0; i < 4; ++i)
        #pragma unroll
        for (int j = 0; j < FN; ++j)
            acc[i][j] = (floatx4)0.f;

    for (int k0 = 0; k0 < K; k0 += 64) {
        int part = k0 / kPerPart;
        int kloc = k0 - part * kPerPart;
        const _Float16* Ap = (part == 0) ? A0 : (part == 1) ? A1 : (part == 2) ? A2 : A3;

        #pragma unroll
        for (int j = 0; j < 4; ++j) {
            int rowblk = (j * 4 + w) * 8;
            const _Float16* src = Ap + (size_t)(row0 + rowblk + srow) * kPerPart + kloc + scol;
            gload_lds16(src, (char*)As + rowblk * 128);
        }
        #pragma unroll
        for (int j = 0; j < BN / 32; ++j) {
            int nblk = (j * 4 + w) * 8;
            const _Float16* src = BT + (size_t)(col0 + nblk + srow) * K + k0 + scol;
            gload_lds16(src, (char*)Bs + nblk * 128);
        }
        asm volatile("s_waitcnt vmcnt(0)" ::: "memory");
        __syncthreads();

        half8 a[2][4];
        half8 b[2][FN];
        #pragma unroll
        for (int kk = 0; kk < 2; ++kk) {
            int kb = kk * 64 + (ksel << 4);
            #pragma unroll
            for (int fm = 0; fm < 4; ++fm) {
                int r = wr * 64 + fm * 16 + mi;
                int byte = kb ^ ((r & 7) << 4);
                a[kk][fm] = *(const half8*)((const char*)As + r * 128 + byte);
            }
            #pragma unroll
            for (int fn = 0; fn < FN; ++fn) {
                int n = wc * WN + fn * 16 + mi;
                int byte = kb ^ ((n & 7) << 4);
                b[kk][fn] = *(const half8*)((const char*)Bs + n * 128 + byte);
            }
        }
        #pragma unroll
        for (int kk = 0; kk < 2; ++kk)
            #pragma unroll
            for (int fm = 0; fm < 4; ++fm)
                #pragma unroll
                for (int fn = 0; fn < FN; ++fn)
                    acc[fm][fn] = __builtin_amdgcn_mfma_f32_16x16x32_f16(
                        a[kk][fm], b[kk][fn], acc[fm][fn], 0, 0, 0);
        __syncthreads();
    }

    #pragma unroll
    for (int fm = 0; fm < 4; ++fm) {
        #pragma unroll
        for (int fn = 0; fn < FN; ++fn) {
            #pragma unroll
            for (int r = 0; r < 4; ++r) {
                int gr = row0 + wr * 64 + fm * 16 + (lane >> 4) * 4 + r;
                int gc = col0 + wc * WN + fn * 16 + (lane & 15);
                if (gr < M && gc < N) {
                    float v = acc[fm][fn][r];
                    if (bias1) v += bias1[gc];
                    out1[(size_t)gr * N + gc] = (_Float16)v;
                }
            }
        }
    }
}

// ---------------------------------------------------------------- SpMM D=256 f16, fused bias+relu+residual

__global__ __launch_bounds__(256) void spmm_epi_f16(const int* __restrict__ rowptr,
                                                    const unsigned* __restrict__ cev,
                                                    const _Float16* __restrict__ Y,
                                                    const float* __restrict__ bias,
                                                    const _Float16* __restrict__ res,
                                                    _Float16* __restrict__ out) {
    int row = (blockIdx.x * blockDim.x + threadIdx.x) >> 6;
    if (row >= N_NODES) return;
    int lane = threadIdx.x & 63;
    int col = lane * 4;
    const _Float16* Ycol = Y + col;
    int beg = rowptr[row];
    int end = rowptr[row + 1];
    float a0 = 0.f, a1 = 0.f, a2 = 0.f, a3 = 0.f;
    int e = beg;
    for (; e + 8 <= end; e += 8) {
        unsigned ev[8];
        #pragma unroll
        for (int j = 0; j < 8; ++j) ev[j] = cev[e + j];
        half4v h[8];
        #pragma unroll
        for (int j = 0; j < 8; ++j)
            h[j] = *(const half4v*)(Ycol + (size_t)(ev[j] & 0xFFFF) * NHID);
        #pragma unroll
        for (int j = 0; j < 8; ++j) {
            float v = cev_val(ev[j]);
            a0 = fmaf(v, (float)h[j][0], a0);
            a1 = fmaf(v, (float)h[j][1], a1);
            a2 = fmaf(v, (float)h[j][2], a2);
            a3 = fmaf(v, (float)h[j][3], a3);
        }
    }
    for (; e < end; ++e) {
        unsigned ev = cev[e];
        float v = cev_val(ev);
        half4v h = *(const half4v*)(Ycol + (size_t)(ev & 0xFFFF) * NHID);
        a0 = fmaf(v, (float)h[0], a0);
        a1 = fmaf(v, (float)h[1], a1);
        a2 = fmaf(v, (float)h[2], a2);
        a3 = fmaf(v, (float)h[3], a3);
    }
    float4 bb = *(const float4*)(bias + col);
    half4v rr = *(const half4v*)(res + (size_t)row * NHID + col);
    half4v o;
    o[0] = (_Float16)(fmaxf(a0 + bb.x, 0.f) + (float)rr[0]);
    o[1] = (_Float16)(fmaxf(a1 + bb.y, 0.f) + (float)rr[1]);
    o[2] = (_Float16)(fmaxf(a2 + bb.z, 0.f) + (float)rr[2]);
    o[3] = (_Float16)(fmaxf(a3 + bb.w, 0.f) + (float)rr[3]);
    *(half4v*)(out + (size_t)row * NHID + col) = o;
}

// ---------------------------------------------------------------- SpMM D=40 (f16 Y) + bias + log_softmax

__global__ __launch_bounds__(256) void spmm40_lsm(const int* __restrict__ rowptr,
                                                  const unsigned* __restrict__ cev,
                                                  const _Float16* __restrict__ Y5,
                                                  const float* __restrict__ bias,
                                                  float* __restrict__ out) {
    int row = (blockIdx.x * blockDim.x + threadIdx.x) >> 6;
    if (row >= N_NODES) return;
    int lane = threadIdx.x & 63;
    bool act = lane < NCLASS;
    const _Float16* Yl = Y5 + lane;
    int beg = rowptr[row];
    int end = rowptr[row + 1];
    float acc = 0.f;
    int e = beg;
    for (; e + 8 <= end; e += 8) {
        unsigned ev[8];
        #pragma unroll
        for (int j = 0; j < 8; ++j) ev[j] = cev[e + j];
        float h[8];
        #pragma unroll
        for (int j = 0; j < 8; ++j)
            h[j] = act ? (float)Yl[(size_t)(ev[j] & 0xFFFF) * NCLASS] : 0.f;
        #pragma unroll
        for (int j = 0; j < 8; ++j) acc = fmaf(cev_val(ev[j]), h[j], acc);
    }
    for (; e < end; ++e) {
        unsigned ev = cev[e];
        float h = act ? (float)Yl[(size_t)(ev & 0xFFFF) * NCLASS] : 0.f;
        acc = fmaf(cev_val(ev), h, acc);
    }
    float x = act ? (acc + bias[lane]) : -INFINITY;
    float m = x;
    #pragma unroll
    for (int off = 32; off > 0; off >>= 1) m = fmaxf(m, __shfl_xor(m, off));
    float ex = act ? __expf(x - m) : 0.f;
    float ssum = ex;
    #pragma unroll
    for (int off = 32; off > 0; off >>= 1) ssum += __shfl_xor(ssum, off);
    float ls = logf(ssum);
    if (act) out[(size_t)row * NCLASS + lane] = x - m - ls;
}

// ---------------------------------------------------------------- launch

extern "C" void kernel_launch(void* const* d_in, const int* in_sizes, int n_in,
                              void* d_out, int out_size, void* d_ws, size_t ws_size,
                              hipStream_t stream) {
    const float* x     = (const float*)d_in[0];
    const int*   esrc  = (const int*)d_in[1];
    const int*   edst  = (const int*)d_in[2];
    const float* evals = (const float*)d_in[3];
    const float* W0 = (const float*)d_in[4];
    const float* b0 = (const float*)d_in[5];
    const float* W1 = (const float*)d_in[6];
    const float* b1 = (const float*)d_in[7];
    const float* W2 = (const float*)d_in[8];
    const float* b2 = (const float*)d_in[9];
    const float* W3 = (const float*)d_in[10];
    const float* b3 = (const float*)d_in[11];
    const float* W5 = (const float*)d_in[12];
    const float* b5 = (const float*)d_in[13];
    float* out = (float*)d_out;

    char* ws = (char*)d_ws;
    size_t off = 0;
    auto alloc = [&](size_t bytes) {
        char* p = ws + off;
        off = (off + bytes + 255) & ~(size_t)255;
        return p;
    };
    _Float16* zh   = (_Float16*)alloc(2ull * N_NODES * NHID);
    _Float16* Yh   = (_Float16*)alloc(2ull * N_NODES * NHID);
    _Float16* x1h  = (_Float16*)alloc(2ull * MPAD * NHID);
    _Float16* x2h  = (_Float16*)alloc(2ull * MPAD * NHID);
    _Float16* x3h  = (_Float16*)alloc(2ull * MPAD * NHID);
    _Float16* x4h  = (_Float16*)alloc(2ull * MPAD * NHID);
    _Float16* Y5h  = (_Float16*)alloc(2ull * N_NODES * NCLASS);
    _Float16* BT01 = (_Float16*)alloc(2ull * 512 * NFEAT);
    _Float16* BT2  = (_Float16*)alloc(2ull * NHID * NHID);
    _Float16* BT3  = (_Float16*)alloc(2ull * NHID * NHID);
    _Float16* BT5  = (_Float16*)alloc(2ull * 64 * 1024);
    int* cnt    = (int*)alloc(sizeof(int) * (N_NODES + NPART));
    int* pcount = cnt + N_NODES;
    int* rowptr = (int*)alloc(sizeof(int) * (N_NODES + 1));
    int* cursor = (int*)alloc(sizeof(int) * N_NODES);
    uint2* plist = (uint2*)alloc(8ull * NPART * PCAP);
    unsigned* cev = (unsigned*)alloc(4ull * N_EDGES);
    (void)ws_size;

    // ---- CSR build (by dst), XCD-partitioned
    zero_i32<<<(N_NODES + NPART + 255) / 256, 256, 0, stream>>>(cnt, N_NODES + NPART);
    bin_kernel<<<(N_EDGES + EPB - 1) / EPB, 256, 0, stream>>>(esrc, edst, evals, cnt, pcount, plist);
    exscan4_kernel<<<1, 1024, 0, stream>>>(cnt, rowptr, cursor, N_NODES);
    pscatter_kernel<<<NPART * BPP, 256, 0, stream>>>(pcount, plist, cursor, cev);

    // ---- weight conversions
    conv_w_kernel<<<(256 * NFEAT + 255) / 256, 256, 0, stream>>>(W0, BT01, NFEAT, NHID, NHID);
    conv_w_kernel<<<(256 * NFEAT + 255) / 256, 256, 0, stream>>>(W1, BT01 + 256 * NFEAT, NFEAT, NHID, NHID);
    conv_w_kernel<<<(NHID * NHID + 255) / 256, 256, 0, stream>>>(W2, BT2, NHID, NHID, NHID);
    conv_w_kernel<<<(NHID * NHID + 255) / 256, 256, 0, stream>>>(W3, BT3, NHID, NHID, NHID);
    conv_w_kernel<<<(64 * 1024 + 255) / 256, 256, 0, stream>>>(W5, BT5, 1024, NCLASS, 64);

    const int mtiles = MPAD / 128;  // 391
    dim3 blk(256);

    // fused: [z | y1] = x @ [W0 | W1]  (A read as f32 directly)
    gemm_xf32<<<dim3(4, mtiles), blk, 0, stream>>>(x, BT01, b0, zh, Yh);
    // x1 = relu(spmm(y1)+b1) + z
    spmm_epi_f16<<<(N_NODES * 64 + 255) / 256, blk, 0, stream>>>(rowptr, cev, Yh, b1, zh, x1h);

    // layer 2
    gemm_f16<128><<<dim3(2, mtiles), blk, 0, stream>>>(x1h, x1h, x1h, x1h, NHID, NHID, BT2,
                                                       nullptr, Yh, N_NODES, NHID);
    spmm_epi_f16<<<(N_NODES * 64 + 255) / 256, blk, 0, stream>>>(rowptr, cev, Yh, b2, x1h, x2h);

    // layer 3 (same W2/b2)
    gemm_f16<128><<<dim3(2, mtiles), blk, 0, stream>>>(x2h, x2h, x2h, x2h, NHID, NHID, BT2,
                                                       nullptr, Yh, N_NODES, NHID);
    spmm_epi_f16<<<(N_NODES * 64 + 255) / 256, blk, 0, stream>>>(rowptr, cev, Yh, b2, x2h, x3h);

    // layer 4
    gemm_f16<128><<<dim3(2, mtiles), blk, 0, stream>>>(x3h, x3h, x3h, x3h, NHID, NHID, BT3,
                                                       nullptr, Yh, N_NODES, NHID);
    spmm_epi_f16<<<(N_NODES * 64 + 255) / 256, blk, 0, stream>>>(rowptr, cev, Yh, b3, x3h, x4h);

    // Y5 = concat(x4,x3,x2,x1) @ W5  (K-concat of 4 parts)
    gemm_f16<64><<<dim3(1, mtiles), blk, 0, stream>>>(x4h, x3h, x2h, x1h, NHID, 4 * NHID, BT5,
                                                      nullptr, Y5h, N_NODES, NCLASS);

    // out = log_softmax(spmm(Y5) + b5)
    spmm40_lsm<<<(N_NODES * 64 + 255) / 256, blk, 0, stream>>>(rowptr, cev, Y5h, b5, out);
}